// Round 3
// baseline (279.991 us; speedup 1.0000x reference)
//
#include <hip/hip_runtime.h>

// STS linear attention, fp32.  B=4, N=4096, H=8, D=64, M=64.
// phase1 : 2048 tiles (one per block, 64 rows each). lane=d, wave w owns 16 m's.
//          Partial KV tiles (33.5 MB) live in d_out; partial Ksum in d_ws.
// phase1b: reduce 64 partials per (b,h) -> KV [32][64][64], Ksum [32][64] in d_ws.
// phase2 : out[n,m] = (sum_d f(Q)[n,d]*KV[m,d]) / (sum_d f(Q)[n,d]*Ksum[d] + eps)
//          no LDS; KV tile is L1/L2-resident.

#define EPSC 1e-6f

constexpr int Bq = 4;
constexpr int Nq = 4096;
constexpr int Hq = 8;
constexpr int Dq = 64;
constexpr int Mq = 64;
constexpr int BH = Bq * Hq;          // 32
constexpr int RSTR = Hq * Dq;        // 512 floats between consecutive n
constexpr int TILESZ = Mq * Dq;      // 4096 floats per tile

__device__ __forceinline__ float fmap(float x) {
    return x > 0.0f ? x + 1.0f : __expf(x);   // elu(x)+1
}

// ---------------- Phase 1: per-block partial KV tiles ----------------
// grid = 2048 blocks x 256 thr (4 waves). Block = tile t: bh = t>>6, rows (t&63)*64..+64.
// Wave w: m0 = 16w. lane = d. acc[16] = KV[m0+mi][lane] partial.
__global__ __launch_bounds__(256)
void phase1_kv(const float* __restrict__ Kp, const float* __restrict__ Vp,
               float* __restrict__ partKV, float* __restrict__ partKS)
{
    const int t  = blockIdx.x;
    const int bh = t >> 6, ck = t & 63;
    const int b  = bh >> 3, h = bh & 7;
    const int w    = threadIdx.x >> 6;
    const int lane = threadIdx.x & 63;
    const int m0   = w * 16;

    const float* Kb = Kp + ((size_t)(b * Nq + ck * 64) * Hq + h) * Dq;
    const float* Vb = Vp + ((size_t)(b * Nq + ck * 64) * Hq + h) * Mq;

    float acc[16];
    #pragma unroll
    for (int i = 0; i < 16; ++i) acc[i] = 0.0f;
    float ksum = 0.0f;

    #pragma unroll 2
    for (int n = 0; n < 64; n += 2) {
        const float k0 = Kb[(size_t)n * RSTR + lane];
        const float k1 = Kb[(size_t)(n + 1) * RSTR + lane];
        const float* v0 = Vb + (size_t)n * RSTR + m0;
        const float* v1 = Vb + (size_t)(n + 1) * RSTR + m0;
        float4 va[4], vb[4];
        #pragma unroll
        for (int j = 0; j < 4; ++j) {
            va[j] = *(const float4*)(v0 + j * 4);
            vb[j] = *(const float4*)(v1 + j * 4);
        }
        const float kf0 = fmap(k0);
        const float kf1 = fmap(k1);
        ksum += kf0 + kf1;
        #pragma unroll
        for (int j = 0; j < 4; ++j) {
            acc[j*4+0] = fmaf(kf0, va[j].x, acc[j*4+0]);
            acc[j*4+1] = fmaf(kf0, va[j].y, acc[j*4+1]);
            acc[j*4+2] = fmaf(kf0, va[j].z, acc[j*4+2]);
            acc[j*4+3] = fmaf(kf0, va[j].w, acc[j*4+3]);
            acc[j*4+0] = fmaf(kf1, vb[j].x, acc[j*4+0]);
            acc[j*4+1] = fmaf(kf1, vb[j].y, acc[j*4+1]);
            acc[j*4+2] = fmaf(kf1, vb[j].z, acc[j*4+2]);
            acc[j*4+3] = fmaf(kf1, vb[j].w, acc[j*4+3]);
        }
    }

    float* dst = partKV + (size_t)t * TILESZ;
    #pragma unroll
    for (int mi = 0; mi < 16; ++mi)
        dst[(m0 + mi) * Dq + lane] = acc[mi];      // coalesced 256 B per store
    if (w == 0)
        partKS[(size_t)t * Dq + lane] = ksum;
}

// ---------------- Phase 1b: reduce 64 partials per bh ----------------
// grid = 512 blocks x 256 thr. block = (bh, sixteenth-of-tile). thread: 64 float4-slots x 4 p-groups.
__global__ __launch_bounds__(256)
void phase1b_reduce(const float* __restrict__ partKV, const float* __restrict__ partKS,
                    float* __restrict__ KV, float* __restrict__ KS)
{
    const int bh = blockIdx.x >> 4, six = blockIdx.x & 15;
    const int f  = threadIdx.x & 63, pg = threadIdx.x >> 6;
    const size_t base = (size_t)bh * 64 * TILESZ + six * 256 + f * 4;

    float4 a = make_float4(0.f, 0.f, 0.f, 0.f);
    #pragma unroll
    for (int p = 0; p < 16; ++p) {
        const float4 v = *(const float4*)(partKV + base + (size_t)(pg * 16 + p) * TILESZ);
        a.x += v.x; a.y += v.y; a.z += v.z; a.w += v.w;
    }

    float ks = 0.0f;
    if (six == 0) {
        #pragma unroll
        for (int p = 0; p < 16; ++p)
            ks += partKS[(size_t)(bh * 64 + pg * 16 + p) * Dq + f];
    }

    __shared__ float4 sred[4][64];
    __shared__ float  sks[4][64];
    sred[pg][f] = a;
    sks[pg][f]  = ks;
    __syncthreads();

    if (pg == 0) {
        float4 r  = sred[0][f];
        const float4 r1 = sred[1][f], r2 = sred[2][f], r3 = sred[3][f];
        r.x += r1.x + r2.x + r3.x;
        r.y += r1.y + r2.y + r3.y;
        r.z += r1.z + r2.z + r3.z;
        r.w += r1.w + r2.w + r3.w;
        *(float4*)(KV + (size_t)bh * TILESZ + six * 256 + f * 4) = r;
        if (six == 0)
            KS[bh * Dq + f] = sks[0][f] + sks[1][f] + sks[2][f] + sks[3][f];
    }
}

// ---------------- Phase 2: out = f(Q) @ KV^T, normalized ----------------
// grid = 1024 blocks x 256 thr. block: bh = blk>>5, rows (blk&31)*128..+128.
// thread: mg = tid&7 -> m = mg*8+mi (8 m's); rt = tid>>3 -> 4 rows. No LDS.
__global__ __launch_bounds__(256)
void phase2_out(const float* __restrict__ Qp, const float* __restrict__ KV,
                const float* __restrict__ KS, float* __restrict__ Out)
{
    const int blk = blockIdx.x;
    const int bh = blk >> 5, ck = blk & 31;
    const int b  = bh >> 3,  h  = bh & 7;
    const int mg = threadIdx.x & 7;
    const int rt = threadIdx.x >> 3;             // 0..31
    const int row0 = ck * 128 + rt * 4;

    const float* Qb  = Qp + ((size_t)(b * Nq + row0) * Hq + h) * Dq;
    const float* KVb = KV + (size_t)bh * TILESZ + mg * 8 * Dq;   // rows m = mg*8+mi
    const float* KSb = KS + bh * Dq;

    float acc[4][8];
    float zac[4] = {0.f, 0.f, 0.f, 0.f};
    #pragma unroll
    for (int i = 0; i < 4; ++i)
        #pragma unroll
        for (int j = 0; j < 8; ++j) acc[i][j] = 0.0f;

    #pragma unroll 4
    for (int d4 = 0; d4 < 16; ++d4) {
        const float4 ks4 = *(const float4*)(KSb + d4 * 4);
        float4 kv[8];
        #pragma unroll
        for (int mi = 0; mi < 8; ++mi)
            kv[mi] = *(const float4*)(KVb + mi * Dq + d4 * 4);   // L1-hot after first waves
        #pragma unroll
        for (int i = 0; i < 4; ++i) {
            const float4 q = *(const float4*)(Qb + (size_t)i * RSTR + d4 * 4);
            const float q0 = fmap(q.x), q1 = fmap(q.y), q2 = fmap(q.z), q3 = fmap(q.w);
            zac[i] = fmaf(q0, ks4.x, zac[i]);
            zac[i] = fmaf(q1, ks4.y, zac[i]);
            zac[i] = fmaf(q2, ks4.z, zac[i]);
            zac[i] = fmaf(q3, ks4.w, zac[i]);
            #pragma unroll
            for (int mi = 0; mi < 8; ++mi) {
                acc[i][mi] = fmaf(q0, kv[mi].x, acc[i][mi]);
                acc[i][mi] = fmaf(q1, kv[mi].y, acc[i][mi]);
                acc[i][mi] = fmaf(q2, kv[mi].z, acc[i][mi]);
                acc[i][mi] = fmaf(q3, kv[mi].w, acc[i][mi]);
            }
        }
    }

    float* Ob = Out + ((size_t)(b * Nq + row0) * Hq + h) * Mq + mg * 8;
    #pragma unroll
    for (int i = 0; i < 4; ++i) {
        const float z = 1.0f / (zac[i] + EPSC);
        const float4 o0 = make_float4(acc[i][0]*z, acc[i][1]*z, acc[i][2]*z, acc[i][3]*z);
        const float4 o1 = make_float4(acc[i][4]*z, acc[i][5]*z, acc[i][6]*z, acc[i][7]*z);
        *(float4*)(Ob + (size_t)i * RSTR)     = o0;
        *(float4*)(Ob + (size_t)i * RSTR + 4) = o1;
    }
}

extern "C" void kernel_launch(void* const* d_in, const int* in_sizes, int n_in,
                              void* d_out, int out_size, void* d_ws, size_t ws_size,
                              hipStream_t stream)
{
    (void)in_sizes; (void)n_in; (void)out_size; (void)ws_size;
    const float* Q = (const float*)d_in[0];
    const float* K = (const float*)d_in[1];
    const float* V = (const float*)d_in[2];
    float* out = (float*)d_out;

    // d_out doubles as scratch for 2048 partial KV tiles (exactly out_size floats).
    float* partKV = out;                                   // [2048][4096] = 33.5 MB
    float* wsKV   = (float*)d_ws;                          // [32][4096]   = 512 KB
    float* wsKS   = wsKV + (size_t)BH * TILESZ;            // [32][64]     = 8 KB
    float* partKS = wsKS + (size_t)BH * Dq;                // [2048][64]   = 512 KB

    phase1_kv<<<2048, 256, 0, stream>>>(K, V, partKV, partKS);
    phase1b_reduce<<<512, 256, 0, stream>>>(partKV, partKS, wsKV, wsKS);
    phase2_out<<<1024, 256, 0, stream>>>(Q, wsKV, wsKS, out);
}